// Round 6
// baseline (752.327 us; speedup 1.0000x reference)
//
#include <hip/hip_runtime.h>
#include <hip/hip_bf16.h>
#include <cstdint>
#include <cstddef>

typedef unsigned short bf16t;
typedef __attribute__((ext_vector_type(8))) short bf16x8;  // 8 bf16 (4 VGPRs)
typedef __attribute__((ext_vector_type(4))) float f32x4;   // MFMA C/D

// ---------- helpers ----------
__device__ __forceinline__ unsigned short f2bf(float f) {
    unsigned u = __float_as_uint(f);
    u += 0x7fffu + ((u >> 16) & 1u);   // RNE
    return (unsigned short)(u >> 16);
}
__device__ __forceinline__ float bf2f(unsigned short h) {
    return __uint_as_float(((unsigned)h) << 16);
}
__device__ __forceinline__ float bflo(unsigned u) { return __uint_as_float(u << 16); }
__device__ __forceinline__ float bfhi(unsigned u) { return __uint_as_float(u & 0xffff0000u); }
__device__ __forceinline__ unsigned pk2(float a, float b) {
    __hip_bfloat162 h = __float22bfloat162_rn(make_float2(a, b));
    return *(unsigned*)&h;
}
__device__ __forceinline__ bf16x8 mk8(unsigned a, unsigned b, unsigned c, unsigned d) {
    union { uint4 u; bf16x8 v; } cv; cv.u = make_uint4(a, b, c, d); return cv.v;
}
__device__ __forceinline__ unsigned fenc(float f) {
    unsigned u = __float_as_uint(f);
    return (u & 0x80000000u) ? ~u : (u | 0x80000000u);
}
__device__ __forceinline__ float fdec(unsigned u) {
    return __uint_as_float((u & 0x80000000u) ? (u ^ 0x80000000u) : ~u);
}

#define HW 65536
#define LOG2E 1.4426950408889634f

// ---------- K1: MFMA 1x1 conv; q outputs pre-scaled by log2e ----------
struct ConvArgs {
    const float* x[2];
    const float* wq[2]; const float* bq[2];
    const float* wk[2]; const float* bk[2];
    const float* wv[2]; const float* bv[2];
    bf16t* q[2]; bf16t* k[2]; bf16t* v[2];
    unsigned* zeroR;    // 7168 B: accum(5120) + accmax(1024) + done(+pad 1024)
};

__global__ __launch_bounds__(256) void conv_qkv(ConvArgs A)
{
    __shared__ __align__(16) bf16t Xlds[256 * 68];   // [px][ch], stride 68

    const int t = threadIdx.x;
    const int z = blockIdx.z;
    const int s = z >> 1, b = z & 1;
    if (z == 0 && blockIdx.x == 0) {
#pragma unroll
        for (int i = 0; i < 7; i++) A.zeroR[t + i * 256] = 0u;
    }
    const int lane = t & 63, wv = t >> 6, quad = lane >> 4, l16 = lane & 15;
    const int px0 = blockIdx.x * 256;

    const float* xp = A.x[s] + (size_t)b * 64 * HW + px0 + t;
    {
        unsigned xw[32];
#pragma unroll
        for (int c = 0; c < 32; c++)
            xw[c] = pk2(xp[(size_t)(2 * c) * HW], xp[(size_t)(2 * c + 1) * HW]);
#pragma unroll
        for (int g = 0; g < 16; g++)
            *(uint2*)&Xlds[t * 68 + g * 4] = make_uint2(xw[2 * g], xw[2 * g + 1]);
    }

    // B-frags (W) + bias + output row pointers: o = ot*16 + l16
    bf16x8 bfr[5][2];
    float bo[5];
    bf16t* obase[5];
#pragma unroll
    for (int ot = 0; ot < 5; ot++) {
        const int o = ot * 16 + l16;
        const float* wrow;
        float wsc = 1.f;
        if (o < 8)       { wrow = A.wq[s] + o * 64;        bo[ot] = A.bq[s][o] * LOG2E; wsc = LOG2E;
                           obase[ot] = A.q[s] + (size_t)(b * 8 + o) * HW; }
        else if (o < 16) { wrow = A.wk[s] + (o - 8) * 64;  bo[ot] = A.bk[s][o - 8];
                           obase[ot] = A.k[s] + (size_t)(b * 8 + o - 8) * HW; }
        else             { wrow = A.wv[s] + (o - 16) * 64; bo[ot] = A.bv[s][o - 16];
                           obase[ot] = A.v[s] + (size_t)(b * 64 + o - 16) * HW; }
#pragma unroll
        for (int ks = 0; ks < 2; ks++) {
            const float* wp = wrow + ks * 32 + quad * 8;
            bfr[ot][ks] = mk8(pk2(wp[0] * wsc, wp[1] * wsc), pk2(wp[2] * wsc, wp[3] * wsc),
                              pk2(wp[4] * wsc, wp[5] * wsc), pk2(wp[6] * wsc, wp[7] * wsc));
        }
    }

    __syncthreads();

    bf16x8 afr[4][2];
#pragma unroll
    for (int i = 0; i < 4; i++)
#pragma unroll
        for (int ks = 0; ks < 2; ks++) {
            const int base = (wv * 64 + i * 16 + l16) * 68 + ks * 32 + quad * 8;
            const uint2 lo = *(const uint2*)&Xlds[base];
            const uint2 hi = *(const uint2*)&Xlds[base + 4];
            afr[i][ks] = mk8(lo.x, lo.y, hi.x, hi.y);
        }

    const f32x4 z4 = {0.f, 0.f, 0.f, 0.f};
    f32x4 acc[4][5];
#pragma unroll
    for (int i = 0; i < 4; i++)
#pragma unroll
        for (int ot = 0; ot < 5; ot++) acc[i][ot] = z4;

#pragma unroll
    for (int ks = 0; ks < 2; ks++)
#pragma unroll
        for (int i = 0; i < 4; i++)
#pragma unroll
            for (int ot = 0; ot < 5; ot++)
                acc[i][ot] = __builtin_amdgcn_mfma_f32_16x16x32_bf16(afr[i][ks], bfr[ot][ks], acc[i][ot], 0, 0, 0);

#pragma unroll
    for (int i = 0; i < 4; i++) {
        const int px = px0 + wv * 64 + i * 16 + quad * 4;
#pragma unroll
        for (int ot = 0; ot < 5; ot++) {
            uint2 u;
            u.x = pk2(acc[i][ot][0] + bo[ot], acc[i][ot][1] + bo[ot]);
            u.y = pk2(acc[i][ot][2] + bo[ot], acc[i][ot][3] + bo[ot]);
            *(uint2*)&obase[ot][px] = u;
        }
    }
}

// ---------- bf16 transpose: per-slice 256x256, 64x64 tiles, z = slice ----------
__global__ __launch_bounds__(256) void transpose16(const bf16t* __restrict__ in, bf16t* __restrict__ out)
{
    __shared__ bf16t tile[64][68];
    const size_t zo = (size_t)blockIdx.z * HW;
    const int i0 = blockIdx.y * 64, j0 = blockIdx.x * 64;
    const int lc = threadIdx.x & 63, rg = threadIdx.x >> 6;
#pragma unroll
    for (int rr = 0; rr < 16; rr++) {
        int row = rg * 16 + rr;
        tile[row][lc] = in[zo + (size_t)(i0 + row) * 256 + j0 + lc];
    }
    __syncthreads();
#pragma unroll
    for (int rr = 0; rr < 16; rr++) {
        int row = rg * 16 + rr;
        out[zo + (size_t)(j0 + row) * 256 + i0 + lc] = tile[lc][row];
    }
}

// ---------- K2: criss-cross rows, pipelined MFMA scores + MFMA PV ----------
// q pre-scaled by log2e -> p = exp2(e). s written coalesced in pass's own frame.
struct RowccArgs {
    const bf16t* q[4]; const bf16t* k[4]; const bf16t* v[4];
    bf16t* o[4]; float* so[4];
};

__global__ __launch_bounds__(256, 2) void rowcc_mfma(RowccArgs P)
{
    // LDS: vs[64][264] (33792) | ps[256][40] (20480) | ks[256][8] (4096) | qs[256][8] (4096) = 62464
    __shared__ __align__(16) char smem[62464];
    bf16t* vs = (bf16t*)smem;
    bf16t* ps = (bf16t*)(smem + 33792);
    bf16t* ks = (bf16t*)(smem + 54272);
    bf16t* qs = (bf16t*)(smem + 58368);

    const int t = threadIdx.x;
    const int r = blockIdx.x, b = blockIdx.y, z = blockIdx.z;
    const bool mask = (z < 2);
    const int lane = t & 63, wv = t >> 6, quad = lane >> 4, l16 = lane & 15;
    const int wband = wv * 64;

    const bf16t* qp = P.q[z];
    const bf16t* kp = P.k[z];
    const bf16t* vp = P.v[z];

    // stage K,Q rows as [pos][ch] via coalesced loads
    const size_t rowb = (size_t)b * 8 * HW + (size_t)r * 256 + t;
    {
        const bf16t* kq = kp + rowb;
        unsigned w0 = (unsigned)kq[0] | ((unsigned)kq[(size_t)HW] << 16);
        unsigned w1 = (unsigned)kq[2 * (size_t)HW] | ((unsigned)kq[3 * (size_t)HW] << 16);
        unsigned w2 = (unsigned)kq[4 * (size_t)HW] | ((unsigned)kq[5 * (size_t)HW] << 16);
        unsigned w3 = (unsigned)kq[6 * (size_t)HW] | ((unsigned)kq[7 * (size_t)HW] << 16);
        *(uint4*)&ks[t * 8] = make_uint4(w0, w1, w2, w3);
        const bf16t* qq = qp + rowb;
        w0 = (unsigned)qq[0] | ((unsigned)qq[(size_t)HW] << 16);
        w1 = (unsigned)qq[2 * (size_t)HW] | ((unsigned)qq[3 * (size_t)HW] << 16);
        w2 = (unsigned)qq[4 * (size_t)HW] | ((unsigned)qq[5 * (size_t)HW] << 16);
        w3 = (unsigned)qq[6 * (size_t)HW] | ((unsigned)qq[7 * (size_t)HW] << 16);
        *(uint4*)&qs[t * 8] = make_uint4(w0, w1, w2, w3);
    }
    // stage V as [c][j] (row stride 264)
    const size_t vb = (size_t)b * 64 * HW + (size_t)r * 256;
#pragma unroll
    for (int i = 0; i < 8; i++) {
        const int qd = i * 256 + t;
        const int c = qd >> 5, jc = (qd & 31) * 8;
        *(uint4*)&vs[c * 264 + jc] = *(const uint4*)&vp[vb + (size_t)c * HW + jc];
    }

    __syncthreads();

    // Q B-frags once (zero quads 1-3 -> effective K=8; K garbage in quads 1-3 is x0)
    const bf16x8 zfr = {0, 0, 0, 0, 0, 0, 0, 0};
    const f32x4 z4 = {0.f, 0.f, 0.f, 0.f};
    bf16x8 qfr[4];
#pragma unroll
    for (int wt = 0; wt < 4; wt++) {
        bf16x8 v8 = *(const bf16x8*)&qs[(wband + wt * 16 + l16) * 8];
        qfr[wt] = (quad == 0) ? v8 : zfr;
    }

    f32x4 acc[4][4];
#pragma unroll
    for (int i = 0; i < 4; i++)
#pragma unroll
        for (int j = 0; j < 4; j++) acc[i][j] = z4;
    float s_t[4] = {0.f, 0.f, 0.f, 0.f};

    auto scores = [&](int jt, f32x4 (&e)[4][2]) {
        bf16x8 kfr0 = *(const bf16x8*)&ks[(jt * 32 + l16) * 8];        // broadcast across quads
        bf16x8 kfr1 = *(const bf16x8*)&ks[(jt * 32 + 16 + l16) * 8];
#pragma unroll
        for (int wt = 0; wt < 4; wt++) {
            e[wt][0] = __builtin_amdgcn_mfma_f32_16x16x32_bf16(kfr0, qfr[wt], z4, 0, 0, 0);
            e[wt][1] = __builtin_amdgcn_mfma_f32_16x16x32_bf16(kfr1, qfr[wt], z4, 0, 0, 0);
        }
    };
    auto expstore = [&](int jt, f32x4 (&e)[4][2]) {
        if (mask && (jt >> 1) == wv) {
            const int j0m = jt * 32;
#pragma unroll
            for (int wt = 0; wt < 4; wt++) {
                const int w_g = wband + wt * 16 + l16;
#pragma unroll
                for (int jtile = 0; jtile < 2; jtile++)
#pragma unroll
                    for (int rr = 0; rr < 4; rr++)
                        if (j0m + jtile * 16 + quad * 4 + rr == w_g) e[wt][jtile][rr] = -3.0e38f;
            }
        }
#pragma unroll
        for (int wt = 0; wt < 4; wt++) {
#pragma unroll
            for (int jtile = 0; jtile < 2; jtile++) {
                const float p0 = __builtin_amdgcn_exp2f(e[wt][jtile][0]);
                const float p1 = __builtin_amdgcn_exp2f(e[wt][jtile][1]);
                const float p2 = __builtin_amdgcn_exp2f(e[wt][jtile][2]);
                const float p3 = __builtin_amdgcn_exp2f(e[wt][jtile][3]);
                s_t[wt] += (p0 + p1) + (p2 + p3);
                uint2 u; u.x = pk2(p0, p1); u.y = pk2(p2, p3);
                *(uint2*)&ps[(wband + wt * 16 + l16) * 40 + jtile * 16 + quad * 4] = u;
            }
        }
    };

    // prologue
    {
        f32x4 e0[4][2];
        scores(0, e0);
        expstore(0, e0);
    }

    for (int jt = 0; jt < 8; jt++) {
        const int j0 = jt * 32;
        bf16x8 afr[4], bfr[4];
#pragma unroll
        for (int wt = 0; wt < 4; wt++)
            afr[wt] = *(const bf16x8*)&ps[(wband + wt * 16 + l16) * 40 + quad * 8];
#pragma unroll
        for (int ct = 0; ct < 4; ct++)
            bfr[ct] = *(const bf16x8*)&vs[(ct * 16 + l16) * 264 + j0 + quad * 8];

        f32x4 en[4][2];
        if (jt < 7) scores(jt + 1, en);

#pragma unroll
        for (int wt = 0; wt < 4; wt++)
#pragma unroll
            for (int ct = 0; ct < 4; ct++)
                acc[wt][ct] = __builtin_amdgcn_mfma_f32_16x16x32_bf16(afr[wt], bfr[ct], acc[wt][ct], 0, 0, 0);

        if (jt < 7) expstore(jt + 1, en);   // ps writes follow this iter's afr reads (in-order DS)
    }

    // denominator: reduce across quads; write coalesced in this pass's frame
#pragma unroll
    for (int wt = 0; wt < 4; wt++) {
        float s = s_t[wt];
        s += __shfl_xor(s, 16, 64);
        s += __shfl_xor(s, 32, 64);
        s_t[wt] = s;
    }
    if (quad == 0) {
#pragma unroll
        for (int wt = 0; wt < 4; wt++) {
            const int w_g = wband + wt * 16 + l16;
            P.so[z][(size_t)b * HW + r * 256 + w_g] = s_t[wt];
        }
    }

    // epilogue: C-layout -> LDS [c][w] -> coalesced global [c][w]
    __syncthreads();
    bf16t* o_lds = (bf16t*)smem;   // overlays vs
#pragma unroll
    for (int wt = 0; wt < 4; wt++) {
        const int w0 = wband + wt * 16 + quad * 4;
#pragma unroll
        for (int ct = 0; ct < 4; ct++) {
            const int c = ct * 16 + l16;
            uint2 u;
            u.x = pk2(acc[wt][ct][0], acc[wt][ct][1]);
            u.y = pk2(acc[wt][ct][2], acc[wt][ct][3]);
            *(uint2*)&o_lds[c * 264 + w0] = u;
        }
    }
    __syncthreads();
    bf16t* ob = P.o[z] + (size_t)b * 64 * HW + (size_t)r * 256;
#pragma unroll
    for (int i = 0; i < 8; i++) {
        const int qd = i * 256 + t;
        const int c = qd >> 5, w8 = (qd & 31) * 8;
        *(uint4*)&ob[(size_t)c * HW + w8] = *(const uint4*)&o_lds[c * 264 + w8];
    }
}

// ---------- K3: combine (reads oH in transposed frame) + stats + last-block gates/BN ----------
__global__ __launch_bounds__(256) void combine_reduce(
    const bf16t* __restrict__ oH1T, const bf16t* __restrict__ oW1,
    const bf16t* __restrict__ oH2T, const bf16t* __restrict__ oW2,
    const float* __restrict__ sH1T, const float* __restrict__ sW1,
    const float* __restrict__ sH2T, const float* __restrict__ sW2,
    const float* __restrict__ x1, const float* __restrict__ x2,
    const float* __restrict__ gamma1, const float* __restrict__ gamma2,
    bf16t* __restrict__ s1, bf16t* __restrict__ s2,
    float* __restrict__ accum, unsigned* __restrict__ accmax, unsigned* __restrict__ done,
    const float* __restrict__ sc1_w1, const float* __restrict__ sc1_b1,
    const float* __restrict__ sc1_w2, const float* __restrict__ sc1_b2,
    const float* __restrict__ sc2_w1, const float* __restrict__ sc2_b1,
    const float* __restrict__ sc2_w2, const float* __restrict__ sc2_b2,
    const float* __restrict__ bn1_scale, const float* __restrict__ bn1_bias,
    const float* __restrict__ bn2_scale, const float* __restrict__ bn2_bias,
    float* __restrict__ gates, float* __restrict__ AB)
{
    const int t = threadIdx.x, chunk = blockIdx.x, c = blockIdx.y, b = blockIdx.z;
    const float g1v = gamma1[0], g2v = gamma2[0];
    const size_t cb = ((size_t)(b * 64 + c)) * HW;
    const size_t pb = (size_t)b * HW;

    float pS1 = 0, pSS1 = 0, pSX1 = 0, pX1 = 0, pXX1 = 0, pM1 = -3e38f;
    float pS2 = 0, pSS2 = 0, pSX2 = 0, pX2 = 0, pXX2 = 0, pM2 = -3e38f;

    for (int i = 0; i < 16; i++) {
        const int h = chunk * 16 + i;
        const int pidx = h * 256 + t;
        const size_t tI = pb + (size_t)t * 256 + h;      // transposed-frame per-pixel
        const size_t trI = cb + (size_t)t * 256 + h;     // transposed-frame per-channel
        const float inv1 = 1.f / (sH1T[tI] + sW1[pb + pidx]);
        const float inv2 = 1.f / (sH2T[tI] + sW2[pb + pidx]);
        const float a1 = (bf2f(oH1T[trI]) + bf2f(oW1[cb + pidx])) * inv1;
        const float a2 = (bf2f(oH2T[trI]) + bf2f(oW2[cb + pidx])) * inv2;
        const float x1v = x1[cb + pidx], x2v = x2[cb + pidx];
        const float s1v = g2v * a2 + x2v + x1v;
        const float s2v = g1v * a1 + x1v + x2v;
        s1[cb + pidx] = f2bf(s1v);
        s2[cb + pidx] = f2bf(s2v);
        pS1 += s1v; pSS1 += s1v * s1v; pSX1 += s1v * x1v; pX1 += x1v; pXX1 += x1v * x1v; pM1 = fmaxf(pM1, s1v);
        pS2 += s2v; pSS2 += s2v * s2v; pSX2 += s2v * x2v; pX2 += x2v; pXX2 += x2v * x2v; pM2 = fmaxf(pM2, s2v);
    }

    __shared__ float wred[12][4];
    float vals[12] = {pS1, pSS1, pSX1, pX1, pXX1, pM1, pS2, pSS2, pSX2, pX2, pXX2, pM2};
    const int lane = t & 63, wave = t >> 6;
#pragma unroll
    for (int iv = 0; iv < 12; iv++) {
        float v = vals[iv];
        const bool isMax = (iv == 5 || iv == 11);
#pragma unroll
        for (int off = 32; off > 0; off >>= 1) {
            const float o = __shfl_down(v, off, 64);
            v = isMax ? fmaxf(v, o) : (v + o);
        }
        if (lane == 0) wred[iv][wave] = v;
    }
    __syncthreads();
    if (t < 12) {
        const bool isMax = (t == 5 || t == 11);
        float v = wred[t][0];
        for (int i = 1; i < 4; i++) v = isMax ? fmaxf(v, wred[t][i]) : (v + wred[t][i]);
        const int stream = (t >= 6) ? 1 : 0;
        const int kk = t - stream * 6;
        if (kk == 5) atomicMax(&accmax[(stream * 2 + b) * 64 + c], fenc(v));
        else atomicAdd(&accum[((stream * 2 + b) * 64 + c) * 5 + kk], v);
    }

    // ---- last block computes gates + BN coefficients ----
    __threadfence();
    __shared__ int lastFlag;
    __syncthreads();
    if (t == 0) lastFlag = (atomicAdd(done, 1u) == 2047u) ? 1 : 0;
    __syncthreads();
    if (!lastFlag) return;
    __threadfence();

    __shared__ float meanS[256], maxS[256], e1S[256], e2S[256];
    {
        const int stream = t >> 7, bb = (t >> 6) & 1, cc = t & 63;
        const float S  = atomicAdd(&accum[t * 5 + 0], 0.f);
        const float SS = atomicAdd(&accum[t * 5 + 1], 0.f);
        const float SX = atomicAdd(&accum[t * 5 + 2], 0.f);
        const float X  = atomicAdd(&accum[t * 5 + 3], 0.f);
        const float XX = atomicAdd(&accum[t * 5 + 4], 0.f);
        meanS[t] = S * (1.f / 65536.f);
        maxS[t] = fdec(atomicAdd(&accmax[t], 0u));
        __syncthreads();

        const float* w1 = stream ? sc2_w1 : sc1_w1;
        const float* b1 = stream ? sc2_b1 : sc1_b1;
        const float* w2 = stream ? sc2_w2 : sc1_w2;
        const float* b2 = stream ? sc2_b2 : sc1_b2;
        float om = b2[cc], ox = b2[cc];
        const int base = stream * 128 + bb * 64;
#pragma unroll
        for (int rr = 0; rr < 4; rr++) {
            float hm = b1[rr], hx = b1[rr];
            for (int c2 = 0; c2 < 64; c2++) {
                hm += w1[rr * 64 + c2] * meanS[base + c2];
                hx += w1[rr * 64 + c2] * maxS[base + c2];
            }
            hm = fmaxf(hm, 0.f); hx = fmaxf(hx, 0.f);
            om += w2[cc * 4 + rr] * hm;
            ox += w2[cc * 4 + rr] * hx;
        }
        const float gate = 1.f / (1.f + __expf(-(om + ox)));
        gates[t] = gate;
        e1S[t] = gate * S + X;
        e2S[t] = gate * gate * SS + 2.f * gate * SX + XX;
        __syncthreads();
        if (bb == 0) {
            const float sumY = e1S[t] + e1S[t + 64];
            const float sumY2 = e2S[t] + e2S[t + 64];
            const float meanY = sumY * (1.f / 131072.f);
            const float varY = sumY2 * (1.f / 131072.f) - meanY * meanY;
            const float sc = stream ? bn2_scale[cc] : bn1_scale[cc];
            const float bi = stream ? bn2_bias[cc] : bn1_bias[cc];
            const float Aa = sc * rsqrtf(varY + 1e-5f);
            AB[stream * 128 + cc] = Aa;
            AB[stream * 128 + 64 + cc] = bi - meanY * Aa;
        }
    }
}

// ---------- K4: final elementwise ----------
__global__ __launch_bounds__(256) void finalize(
    const bf16t* __restrict__ s1, const bf16t* __restrict__ s2,
    const float* __restrict__ x1, const float* __restrict__ x2,
    const float* __restrict__ gates, const float* __restrict__ AB,
    float* __restrict__ out)
{
    const size_t tid = (size_t)blockIdx.x * 256 + threadIdx.x;
    const size_t idx = tid * 4;
    const int b = (int)(idx >> 22);
    const int c = (int)((idx >> 16) & 63);
    const bool odd = (c & 1) != 0;
    const float g1 = gates[b * 64 + c], g2 = gates[128 + b * 64 + c];
    const float A1 = AB[c], B1 = AB[64 + c], A2 = AB[128 + c], B2 = AB[192 + c];

    const uint2 su1 = *(const uint2*)(s1 + idx);
    const uint2 su2 = *(const uint2*)(s2 + idx);
    const float4 x1v = *(const float4*)(x1 + idx);
    const float4 x2v = *(const float4*)(x2 + idx);
    float s1f[4] = {bflo(su1.x), bfhi(su1.x), bflo(su1.y), bfhi(su1.y)};
    float s2f[4] = {bflo(su2.x), bfhi(su2.x), bflo(su2.y), bfhi(su2.y)};
    float xa[4] = {x1v.x, x1v.y, x1v.z, x1v.w};
    float xb[4] = {x2v.x, x2v.y, x2v.z, x2v.w};
    float o1[4], o2[4];
#pragma unroll
    for (int j = 0; j < 4; j++) {
        const float y1 = g1 * s1f[j] + xa[j];
        const float y2 = g2 * s2f[j] + xb[j];
        o1[j] = odd ? fmaxf(A1 * y1 + B1, 0.f) : xa[j];
        o2[j] = odd ? fmaxf(A2 * y2 + B2, 0.f) : xb[j];
    }
    *(float4*)(out + idx) = make_float4(o1[0], o1[1], o1[2], o1[3]);
    *(float4*)(out + 8388608 + idx) = make_float4(o2[0], o2[1], o2[2], o2[3]);
}

// ---------- host ----------
extern "C" void kernel_launch(void* const* d_in, const int* in_sizes, int n_in,
                              void* d_out, int out_size, void* d_ws, size_t ws_size,
                              hipStream_t stream) {
    (void)in_sizes; (void)n_in; (void)out_size; (void)ws_size;
    const float* x1 = (const float*)d_in[0];
    const float* x2 = (const float*)d_in[1];
    const float* wq1 = (const float*)d_in[2];  const float* bq1 = (const float*)d_in[3];
    const float* wq2 = (const float*)d_in[4];  const float* bq2 = (const float*)d_in[5];
    const float* wk1 = (const float*)d_in[6];  const float* bk1 = (const float*)d_in[7];
    const float* wk2 = (const float*)d_in[8];  const float* bk2 = (const float*)d_in[9];
    const float* wv1 = (const float*)d_in[10]; const float* bv1 = (const float*)d_in[11];
    const float* wv2 = (const float*)d_in[12]; const float* bv2 = (const float*)d_in[13];
    const float* gamma1 = (const float*)d_in[14];
    const float* gamma2 = (const float*)d_in[15];
    const float* sc1_w1 = (const float*)d_in[16]; const float* sc1_b1 = (const float*)d_in[17];
    const float* sc1_w2 = (const float*)d_in[18]; const float* sc1_b2 = (const float*)d_in[19];
    const float* sc2_w1 = (const float*)d_in[20]; const float* sc2_b1 = (const float*)d_in[21];
    const float* sc2_w2 = (const float*)d_in[22]; const float* sc2_b2 = (const float*)d_in[23];
    const float* bn1_scale = (const float*)d_in[24]; const float* bn1_bias = (const float*)d_in[25];
    const float* bn2_scale = (const float*)d_in[26]; const float* bn2_bias = (const float*)d_in[27];

    char* p = (char*)d_ws;
    const size_t SZ_QK = 2097152;   // bf16 (B,8,H,W)
    const size_t SZ_V = 16777216;   // bf16 (B,64,H,W)
    const size_t SZ_ST = 524288;    // fp32 (B,H,W)

    // contiguous input block for single-transpose dispatch: q1,k1,q2,k2,v1,v2
    bf16t* q1 = (bf16t*)(p + 0 * SZ_QK);
    bf16t* k1 = (bf16t*)(p + 1 * SZ_QK);
    bf16t* q2 = (bf16t*)(p + 2 * SZ_QK);
    bf16t* k2 = (bf16t*)(p + 3 * SZ_QK);
    bf16t* v1 = (bf16t*)(p + 4 * SZ_QK);
    bf16t* v2 = (bf16t*)(p + 4 * SZ_QK + SZ_V);
    size_t off = 4 * SZ_QK + 2 * SZ_V;
    bf16t* q1T = (bf16t*)(p + off + 0 * SZ_QK);
    bf16t* k1T = (bf16t*)(p + off + 1 * SZ_QK);
    bf16t* q2T = (bf16t*)(p + off + 2 * SZ_QK);
    bf16t* k2T = (bf16t*)(p + off + 3 * SZ_QK);
    bf16t* v1T = (bf16t*)(p + off + 4 * SZ_QK);
    bf16t* v2T = (bf16t*)(p + off + 4 * SZ_QK + SZ_V);
    off += 4 * SZ_QK + 2 * SZ_V;
    bf16t* oH1T = (bf16t*)(p + off); off += SZ_V;
    bf16t* oH2T = (bf16t*)(p + off); off += SZ_V;
    bf16t* oW1 = (bf16t*)(p + off); off += SZ_V;
    bf16t* oW2 = (bf16t*)(p + off); off += SZ_V;
    float* sH1 = (float*)(p + off); off += SZ_ST;   // column-pass frame (coalesced)
    float* sH2 = (float*)(p + off); off += SZ_ST;
    float* sW1 = (float*)(p + off); off += SZ_ST;
    float* sW2 = (float*)(p + off); off += SZ_ST;
    float* accum = (float*)(p + off);                  // 1280 f32
    unsigned* accmax = (unsigned*)(p + off + 5120);    // 256 u32
    unsigned* done = (unsigned*)(p + off + 6144);      // 1 u32 (+pad)
    float* gates = (float*)(p + off + 7168);
    float* AB = (float*)(p + off + 8192);

    // s1/s2 overlay the dead v1T/v2T (oH1T/oH2T must survive into combine)
    bf16t* s1 = v1T;
    bf16t* s2 = v2T;

    // K1: MFMA convs (+ accum/done zeroing)
    ConvArgs CA;
    CA.x[0] = x1; CA.x[1] = x2;
    CA.wq[0] = wq1; CA.wq[1] = wq2; CA.bq[0] = bq1; CA.bq[1] = bq2;
    CA.wk[0] = wk1; CA.wk[1] = wk2; CA.bk[0] = bk1; CA.bk[1] = bk2;
    CA.wv[0] = wv1; CA.wv[1] = wv2; CA.bv[0] = bv1; CA.bv[1] = bv2;
    CA.q[0] = q1; CA.q[1] = q2; CA.k[0] = k1; CA.k[1] = k2;
    CA.v[0] = v1; CA.v[1] = v2;
    CA.zeroR = (unsigned*)accum;
    conv_qkv<<<dim3(256, 1, 4), 256, 0, stream>>>(CA);

    // K2: all input transposes (q1..k2 = 64 slices, v1,v2 = 256)
    transpose16<<<dim3(4, 4, 320), 256, 0, stream>>>(q1, q1T);

    // K3: fused criss-cross
    RowccArgs RA;
    RA.q[0] = q2T; RA.k[0] = k1T; RA.v[0] = v1T; RA.o[0] = oH1T; RA.so[0] = sH1;
    RA.q[1] = q1T; RA.k[1] = k2T; RA.v[1] = v2T; RA.o[1] = oH2T; RA.so[1] = sH2;
    RA.q[2] = q2;  RA.k[2] = k1;  RA.v[2] = v1;  RA.o[2] = oW1;  RA.so[2] = sW1;
    RA.q[3] = q1;  RA.k[3] = k2;  RA.v[3] = v2;  RA.o[3] = oW2;  RA.so[3] = sW2;
    rowcc_mfma<<<dim3(256, 2, 4), 256, 0, stream>>>(RA);

    // K4: combine (+ last-block gates/BN)
    combine_reduce<<<dim3(16, 64, 2), 256, 0, stream>>>(
        oH1T, oW1, oH2T, oW2, sH1, sW1, sH2, sW2, x1, x2, gamma1, gamma2,
        s1, s2, accum, accmax, done,
        sc1_w1, sc1_b1, sc1_w2, sc1_b2,
        sc2_w1, sc2_b1, sc2_w2, sc2_b2,
        bn1_scale, bn1_bias, bn2_scale, bn2_bias,
        gates, AB);

    // K5: finalize
    finalize<<<8192, 256, 0, stream>>>(s1, s2, x1, x2, gates, AB, (float*)d_out);
}

// Round 7
// 381.515 us; speedup vs baseline: 1.9719x; 1.9719x over previous
//
#include <hip/hip_runtime.h>
#include <hip/hip_bf16.h>
#include <cstdint>
#include <cstddef>

typedef unsigned short bf16t;
typedef __attribute__((ext_vector_type(8))) short bf16x8;  // 8 bf16 (4 VGPRs)
typedef __attribute__((ext_vector_type(4))) float f32x4;   // MFMA C/D

// ---------- helpers ----------
__device__ __forceinline__ unsigned short f2bf(float f) {
    unsigned u = __float_as_uint(f);
    u += 0x7fffu + ((u >> 16) & 1u);   // RNE
    return (unsigned short)(u >> 16);
}
__device__ __forceinline__ float bf2f(unsigned short h) {
    return __uint_as_float(((unsigned)h) << 16);
}
__device__ __forceinline__ float bflo(unsigned u) { return __uint_as_float(u << 16); }
__device__ __forceinline__ float bfhi(unsigned u) { return __uint_as_float(u & 0xffff0000u); }
__device__ __forceinline__ unsigned pk2(float a, float b) {
    __hip_bfloat162 h = __float22bfloat162_rn(make_float2(a, b));
    return *(unsigned*)&h;
}
__device__ __forceinline__ bf16x8 mk8(unsigned a, unsigned b, unsigned c, unsigned d) {
    union { uint4 u; bf16x8 v; } cv; cv.u = make_uint4(a, b, c, d); return cv.v;
}
__device__ __forceinline__ unsigned fenc(float f) {
    unsigned u = __float_as_uint(f);
    return (u & 0x80000000u) ? ~u : (u | 0x80000000u);
}
__device__ __forceinline__ float fdec(unsigned u) {
    return __uint_as_float((u & 0x80000000u) ? (u ^ 0x80000000u) : ~u);
}

#define HW 65536
#define LOG2E 1.4426950408889634f

// ---------- K1: MFMA 1x1 conv; q outputs pre-scaled by log2e ----------
struct ConvArgs {
    const float* x[2];
    const float* wq[2]; const float* bq[2];
    const float* wk[2]; const float* bk[2];
    const float* wv[2]; const float* bv[2];
    bf16t* q[2]; bf16t* k[2]; bf16t* v[2];
    unsigned* zeroR;    // 7168 B: accum(5120) + accmax(1024) + done(+pad 1024)
};

__global__ __launch_bounds__(256) void conv_qkv(ConvArgs A)
{
    __shared__ __align__(16) bf16t Xlds[256 * 68];   // [px][ch], stride 68

    const int t = threadIdx.x;
    const int z = blockIdx.z;
    const int s = z >> 1, b = z & 1;
    if (z == 0 && blockIdx.x == 0) {
#pragma unroll
        for (int i = 0; i < 7; i++) A.zeroR[t + i * 256] = 0u;
    }
    const int lane = t & 63, wv = t >> 6, quad = lane >> 4, l16 = lane & 15;
    const int px0 = blockIdx.x * 256;

    const float* xp = A.x[s] + (size_t)b * 64 * HW + px0 + t;
    {
        unsigned xw[32];
#pragma unroll
        for (int c = 0; c < 32; c++)
            xw[c] = pk2(xp[(size_t)(2 * c) * HW], xp[(size_t)(2 * c + 1) * HW]);
#pragma unroll
        for (int g = 0; g < 16; g++)
            *(uint2*)&Xlds[t * 68 + g * 4] = make_uint2(xw[2 * g], xw[2 * g + 1]);
    }

    // B-frags (W) + bias + output row pointers: o = ot*16 + l16
    bf16x8 bfr[5][2];
    float bo[5];
    bf16t* obase[5];
#pragma unroll
    for (int ot = 0; ot < 5; ot++) {
        const int o = ot * 16 + l16;
        const float* wrow;
        float wsc = 1.f;
        if (o < 8)       { wrow = A.wq[s] + o * 64;        bo[ot] = A.bq[s][o] * LOG2E; wsc = LOG2E;
                           obase[ot] = A.q[s] + (size_t)(b * 8 + o) * HW; }
        else if (o < 16) { wrow = A.wk[s] + (o - 8) * 64;  bo[ot] = A.bk[s][o - 8];
                           obase[ot] = A.k[s] + (size_t)(b * 8 + o - 8) * HW; }
        else             { wrow = A.wv[s] + (o - 16) * 64; bo[ot] = A.bv[s][o - 16];
                           obase[ot] = A.v[s] + (size_t)(b * 64 + o - 16) * HW; }
#pragma unroll
        for (int ks = 0; ks < 2; ks++) {
            const float* wp = wrow + ks * 32 + quad * 8;
            bfr[ot][ks] = mk8(pk2(wp[0] * wsc, wp[1] * wsc), pk2(wp[2] * wsc, wp[3] * wsc),
                              pk2(wp[4] * wsc, wp[5] * wsc), pk2(wp[6] * wsc, wp[7] * wsc));
        }
    }

    __syncthreads();

    bf16x8 afr[4][2];
#pragma unroll
    for (int i = 0; i < 4; i++)
#pragma unroll
        for (int ks = 0; ks < 2; ks++) {
            const int base = (wv * 64 + i * 16 + l16) * 68 + ks * 32 + quad * 8;
            const uint2 lo = *(const uint2*)&Xlds[base];
            const uint2 hi = *(const uint2*)&Xlds[base + 4];
            afr[i][ks] = mk8(lo.x, lo.y, hi.x, hi.y);
        }

    const f32x4 z4 = {0.f, 0.f, 0.f, 0.f};
    f32x4 acc[4][5];
#pragma unroll
    for (int i = 0; i < 4; i++)
#pragma unroll
        for (int ot = 0; ot < 5; ot++) acc[i][ot] = z4;

#pragma unroll
    for (int ks = 0; ks < 2; ks++)
#pragma unroll
        for (int i = 0; i < 4; i++)
#pragma unroll
            for (int ot = 0; ot < 5; ot++)
                acc[i][ot] = __builtin_amdgcn_mfma_f32_16x16x32_bf16(afr[i][ks], bfr[ot][ks], acc[i][ot], 0, 0, 0);

#pragma unroll
    for (int i = 0; i < 4; i++) {
        const int px = px0 + wv * 64 + i * 16 + quad * 4;
#pragma unroll
        for (int ot = 0; ot < 5; ot++) {
            uint2 u;
            u.x = pk2(acc[i][ot][0] + bo[ot], acc[i][ot][1] + bo[ot]);
            u.y = pk2(acc[i][ot][2] + bo[ot], acc[i][ot][3] + bo[ot]);
            *(uint2*)&obase[ot][px] = u;
        }
    }
}

// ---------- bf16 transpose: per-slice 256x256, 64x64 tiles, z = slice ----------
__global__ __launch_bounds__(256) void transpose16(const bf16t* __restrict__ in, bf16t* __restrict__ out)
{
    __shared__ bf16t tile[64][68];
    const size_t zo = (size_t)blockIdx.z * HW;
    const int i0 = blockIdx.y * 64, j0 = blockIdx.x * 64;
    const int lc = threadIdx.x & 63, rg = threadIdx.x >> 6;
#pragma unroll
    for (int rr = 0; rr < 16; rr++) {
        int row = rg * 16 + rr;
        tile[row][lc] = in[zo + (size_t)(i0 + row) * 256 + j0 + lc];
    }
    __syncthreads();
#pragma unroll
    for (int rr = 0; rr < 16; rr++) {
        int row = rg * 16 + rr;
        out[zo + (size_t)(j0 + row) * 256 + i0 + lc] = tile[lc][row];
    }
}

// ---------- K2: criss-cross rows, pipelined MFMA scores + MFMA PV ----------
struct RowccArgs {
    const bf16t* q[4]; const bf16t* k[4]; const bf16t* v[4];
    bf16t* o[4]; float* so[4];
};

__global__ __launch_bounds__(256, 2) void rowcc_mfma(RowccArgs P)
{
    // LDS: vs[64][264] (33792) | ps[256][40] (20480) | ks[256][8] (4096) | qs[256][8] (4096) = 62464
    __shared__ __align__(16) char smem[62464];
    bf16t* vs = (bf16t*)smem;
    bf16t* ps = (bf16t*)(smem + 33792);
    bf16t* ks = (bf16t*)(smem + 54272);
    bf16t* qs = (bf16t*)(smem + 58368);

    const int t = threadIdx.x;
    const int r = blockIdx.x, b = blockIdx.y, z = blockIdx.z;
    const bool mask = (z < 2);
    const int lane = t & 63, wv = t >> 6, quad = lane >> 4, l16 = lane & 15;
    const int wband = wv * 64;

    const bf16t* qp = P.q[z];
    const bf16t* kp = P.k[z];
    const bf16t* vp = P.v[z];

    const size_t rowb = (size_t)b * 8 * HW + (size_t)r * 256 + t;
    {
        const bf16t* kq = kp + rowb;
        unsigned w0 = (unsigned)kq[0] | ((unsigned)kq[(size_t)HW] << 16);
        unsigned w1 = (unsigned)kq[2 * (size_t)HW] | ((unsigned)kq[3 * (size_t)HW] << 16);
        unsigned w2 = (unsigned)kq[4 * (size_t)HW] | ((unsigned)kq[5 * (size_t)HW] << 16);
        unsigned w3 = (unsigned)kq[6 * (size_t)HW] | ((unsigned)kq[7 * (size_t)HW] << 16);
        *(uint4*)&ks[t * 8] = make_uint4(w0, w1, w2, w3);
        const bf16t* qq = qp + rowb;
        w0 = (unsigned)qq[0] | ((unsigned)qq[(size_t)HW] << 16);
        w1 = (unsigned)qq[2 * (size_t)HW] | ((unsigned)qq[3 * (size_t)HW] << 16);
        w2 = (unsigned)qq[4 * (size_t)HW] | ((unsigned)qq[5 * (size_t)HW] << 16);
        w3 = (unsigned)qq[6 * (size_t)HW] | ((unsigned)qq[7 * (size_t)HW] << 16);
        *(uint4*)&qs[t * 8] = make_uint4(w0, w1, w2, w3);
    }
    const size_t vb = (size_t)b * 64 * HW + (size_t)r * 256;
#pragma unroll
    for (int i = 0; i < 8; i++) {
        const int qd = i * 256 + t;
        const int c = qd >> 5, jc = (qd & 31) * 8;
        *(uint4*)&vs[c * 264 + jc] = *(const uint4*)&vp[vb + (size_t)c * HW + jc];
    }

    __syncthreads();

    const bf16x8 zfr = {0, 0, 0, 0, 0, 0, 0, 0};
    const f32x4 z4 = {0.f, 0.f, 0.f, 0.f};
    bf16x8 qfr[4];
#pragma unroll
    for (int wt = 0; wt < 4; wt++) {
        bf16x8 v8 = *(const bf16x8*)&qs[(wband + wt * 16 + l16) * 8];
        qfr[wt] = (quad == 0) ? v8 : zfr;
    }

    f32x4 acc[4][4];
#pragma unroll
    for (int i = 0; i < 4; i++)
#pragma unroll
        for (int j = 0; j < 4; j++) acc[i][j] = z4;
    float s_t[4] = {0.f, 0.f, 0.f, 0.f};

    auto scores = [&](int jt, f32x4 (&e)[4][2]) {
        bf16x8 kfr0 = *(const bf16x8*)&ks[(jt * 32 + l16) * 8];
        bf16x8 kfr1 = *(const bf16x8*)&ks[(jt * 32 + 16 + l16) * 8];
#pragma unroll
        for (int wt = 0; wt < 4; wt++) {
            e[wt][0] = __builtin_amdgcn_mfma_f32_16x16x32_bf16(kfr0, qfr[wt], z4, 0, 0, 0);
            e[wt][1] = __builtin_amdgcn_mfma_f32_16x16x32_bf16(kfr1, qfr[wt], z4, 0, 0, 0);
        }
    };
    auto expstore = [&](int jt, f32x4 (&e)[4][2]) {
        if (mask && (jt >> 1) == wv) {
            const int j0m = jt * 32;
#pragma unroll
            for (int wt = 0; wt < 4; wt++) {
                const int w_g = wband + wt * 16 + l16;
#pragma unroll
                for (int jtile = 0; jtile < 2; jtile++)
#pragma unroll
                    for (int rr = 0; rr < 4; rr++)
                        if (j0m + jtile * 16 + quad * 4 + rr == w_g) e[wt][jtile][rr] = -3.0e38f;
            }
        }
#pragma unroll
        for (int wt = 0; wt < 4; wt++) {
#pragma unroll
            for (int jtile = 0; jtile < 2; jtile++) {
                const float p0 = __builtin_amdgcn_exp2f(e[wt][jtile][0]);
                const float p1 = __builtin_amdgcn_exp2f(e[wt][jtile][1]);
                const float p2 = __builtin_amdgcn_exp2f(e[wt][jtile][2]);
                const float p3 = __builtin_amdgcn_exp2f(e[wt][jtile][3]);
                s_t[wt] += (p0 + p1) + (p2 + p3);
                uint2 u; u.x = pk2(p0, p1); u.y = pk2(p2, p3);
                *(uint2*)&ps[(wband + wt * 16 + l16) * 40 + jtile * 16 + quad * 4] = u;
            }
        }
    };

    {
        f32x4 e0[4][2];
        scores(0, e0);
        expstore(0, e0);
    }

    for (int jt = 0; jt < 8; jt++) {
        const int j0 = jt * 32;
        bf16x8 afr[4], bfr[4];
#pragma unroll
        for (int wt = 0; wt < 4; wt++)
            afr[wt] = *(const bf16x8*)&ps[(wband + wt * 16 + l16) * 40 + quad * 8];
#pragma unroll
        for (int ct = 0; ct < 4; ct++)
            bfr[ct] = *(const bf16x8*)&vs[(ct * 16 + l16) * 264 + j0 + quad * 8];

        f32x4 en[4][2];
        if (jt < 7) scores(jt + 1, en);

#pragma unroll
        for (int wt = 0; wt < 4; wt++)
#pragma unroll
            for (int ct = 0; ct < 4; ct++)
                acc[wt][ct] = __builtin_amdgcn_mfma_f32_16x16x32_bf16(afr[wt], bfr[ct], acc[wt][ct], 0, 0, 0);

        if (jt < 7) expstore(jt + 1, en);
    }

#pragma unroll
    for (int wt = 0; wt < 4; wt++) {
        float s = s_t[wt];
        s += __shfl_xor(s, 16, 64);
        s += __shfl_xor(s, 32, 64);
        s_t[wt] = s;
    }
    if (quad == 0) {
#pragma unroll
        for (int wt = 0; wt < 4; wt++) {
            const int w_g = wband + wt * 16 + l16;
            P.so[z][(size_t)b * HW + r * 256 + w_g] = s_t[wt];
        }
    }

    __syncthreads();
    bf16t* o_lds = (bf16t*)smem;   // overlays vs
#pragma unroll
    for (int wt = 0; wt < 4; wt++) {
        const int w0 = wband + wt * 16 + quad * 4;
#pragma unroll
        for (int ct = 0; ct < 4; ct++) {
            const int c = ct * 16 + l16;
            uint2 u;
            u.x = pk2(acc[wt][ct][0], acc[wt][ct][1]);
            u.y = pk2(acc[wt][ct][2], acc[wt][ct][3]);
            *(uint2*)&o_lds[c * 264 + w0] = u;
        }
    }
    __syncthreads();
    bf16t* ob = P.o[z] + (size_t)b * 64 * HW + (size_t)r * 256;
#pragma unroll
    for (int i = 0; i < 8; i++) {
        const int qd = i * 256 + t;
        const int c = qd >> 5, w8 = (qd & 31) * 8;
        *(uint4*)&ob[(size_t)c * HW + w8] = *(const uint4*)&o_lds[c * 264 + w8];
    }
}

// ---------- K3: combine — register-transposed oH reads (1 full line/thread) ----------
// grid (8 h-tiles, 64 c, 2 b); thread t owns column w=t, h = hc*32..+31.
__global__ __launch_bounds__(256) void combine_reduce(
    const bf16t* __restrict__ oH1T, const bf16t* __restrict__ oW1,
    const bf16t* __restrict__ oH2T, const bf16t* __restrict__ oW2,
    const float* __restrict__ sH1T, const float* __restrict__ sW1,
    const float* __restrict__ sH2T, const float* __restrict__ sW2,
    const float* __restrict__ x1, const float* __restrict__ x2,
    const float* __restrict__ gamma1, const float* __restrict__ gamma2,
    bf16t* __restrict__ s1, bf16t* __restrict__ s2,
    float* __restrict__ accum, unsigned* __restrict__ accmax, unsigned* __restrict__ done,
    const float* __restrict__ sc1_w1, const float* __restrict__ sc1_b1,
    const float* __restrict__ sc1_w2, const float* __restrict__ sc1_b2,
    const float* __restrict__ sc2_w1, const float* __restrict__ sc2_b1,
    const float* __restrict__ sc2_w2, const float* __restrict__ sc2_b2,
    const float* __restrict__ bn1_scale, const float* __restrict__ bn1_bias,
    const float* __restrict__ bn2_scale, const float* __restrict__ bn2_bias,
    float* __restrict__ gates, float* __restrict__ AB)
{
    const int t = threadIdx.x, hc = blockIdx.x, c = blockIdx.y, b = blockIdx.z;
    const float g1v = gamma1[0], g2v = gamma2[0];
    const size_t cb = ((size_t)(b * 64 + c)) * HW;
    const size_t pb = (size_t)b * HW;
    const int h0 = hc * 32;
    const size_t tb = (size_t)t * 256 + h0;    // transposed-frame base [w=t][h0]

    // one full 64B line per tensor per thread
    union { uint4 q[4]; unsigned w[16]; } U1, U2;
#pragma unroll
    for (int i = 0; i < 4; i++) {
        U1.q[i] = *(const uint4*)&oH1T[cb + tb + i * 8];
        U2.q[i] = *(const uint4*)&oH2T[cb + tb + i * 8];
    }
    union { float4 q[8]; float f[32]; } D1, D2;
#pragma unroll
    for (int i = 0; i < 8; i++) {
        D1.q[i] = *(const float4*)&sH1T[pb + tb + i * 4];
        D2.q[i] = *(const float4*)&sH2T[pb + tb + i * 4];
    }

    float pS1 = 0, pSS1 = 0, pSX1 = 0, pX1 = 0, pXX1 = 0, pM1 = -3e38f;
    float pS2 = 0, pSS2 = 0, pSX2 = 0, pX2 = 0, pXX2 = 0, pM2 = -3e38f;

#pragma unroll
    for (int j = 0; j < 32; j++) {
        const int pidx = (h0 + j) * 256 + t;
        const unsigned u1 = U1.w[j >> 1], u2 = U2.w[j >> 1];
        const float oh1v = (j & 1) ? bfhi(u1) : bflo(u1);
        const float oh2v = (j & 1) ? bfhi(u2) : bflo(u2);
        const float inv1 = 1.f / (D1.f[j] + sW1[pb + pidx]);
        const float inv2 = 1.f / (D2.f[j] + sW2[pb + pidx]);
        const float a1 = (oh1v + bf2f(oW1[cb + pidx])) * inv1;
        const float a2 = (oh2v + bf2f(oW2[cb + pidx])) * inv2;
        const float x1v = x1[cb + pidx], x2v = x2[cb + pidx];
        const float s1v = g2v * a2 + x2v + x1v;
        const float s2v = g1v * a1 + x1v + x2v;
        s1[cb + pidx] = f2bf(s1v);
        s2[cb + pidx] = f2bf(s2v);
        pS1 += s1v; pSS1 += s1v * s1v; pSX1 += s1v * x1v; pX1 += x1v; pXX1 += x1v * x1v; pM1 = fmaxf(pM1, s1v);
        pS2 += s2v; pSS2 += s2v * s2v; pSX2 += s2v * x2v; pX2 += x2v; pXX2 += x2v * x2v; pM2 = fmaxf(pM2, s2v);
    }

    __shared__ float wred[12][4];
    float vals[12] = {pS1, pSS1, pSX1, pX1, pXX1, pM1, pS2, pSS2, pSX2, pX2, pXX2, pM2};
    const int lane = t & 63, wave = t >> 6;
#pragma unroll
    for (int iv = 0; iv < 12; iv++) {
        float v = vals[iv];
        const bool isMax = (iv == 5 || iv == 11);
#pragma unroll
        for (int off = 32; off > 0; off >>= 1) {
            const float o = __shfl_down(v, off, 64);
            v = isMax ? fmaxf(v, o) : (v + o);
        }
        if (lane == 0) wred[iv][wave] = v;
    }
    __syncthreads();
    if (t < 12) {
        const bool isMax = (t == 5 || t == 11);
        float v = wred[t][0];
        for (int i = 1; i < 4; i++) v = isMax ? fmaxf(v, wred[t][i]) : (v + wred[t][i]);
        const int stream = (t >= 6) ? 1 : 0;
        const int kk = t - stream * 6;
        if (kk == 5) atomicMax(&accmax[(stream * 2 + b) * 64 + c], fenc(v));
        else atomicAdd(&accum[((stream * 2 + b) * 64 + c) * 5 + kk], v);
    }

    // ---- last block (of 1024) computes gates + BN coefficients ----
    __threadfence();
    __shared__ int lastFlag;
    __syncthreads();
    if (t == 0) lastFlag = (atomicAdd(done, 1u) == 1023u) ? 1 : 0;
    __syncthreads();
    if (!lastFlag) return;
    __threadfence();

    __shared__ float meanS[256], maxS[256], e1S[256], e2S[256];
    {
        const int stream = t >> 7, bb = (t >> 6) & 1, cc = t & 63;
        const float S  = atomicAdd(&accum[t * 5 + 0], 0.f);
        const float SS = atomicAdd(&accum[t * 5 + 1], 0.f);
        const float SX = atomicAdd(&accum[t * 5 + 2], 0.f);
        const float X  = atomicAdd(&accum[t * 5 + 3], 0.f);
        const float XX = atomicAdd(&accum[t * 5 + 4], 0.f);
        meanS[t] = S * (1.f / 65536.f);
        maxS[t] = fdec(atomicAdd(&accmax[t], 0u));
        __syncthreads();

        const float* w1 = stream ? sc2_w1 : sc1_w1;
        const float* b1 = stream ? sc2_b1 : sc1_b1;
        const float* w2 = stream ? sc2_w2 : sc1_w2;
        const float* b2 = stream ? sc2_b2 : sc1_b2;
        float om = b2[cc], ox = b2[cc];
        const int base = stream * 128 + bb * 64;
#pragma unroll
        for (int rr = 0; rr < 4; rr++) {
            float hm = b1[rr], hx = b1[rr];
            for (int c2 = 0; c2 < 64; c2++) {
                hm += w1[rr * 64 + c2] * meanS[base + c2];
                hx += w1[rr * 64 + c2] * maxS[base + c2];
            }
            hm = fmaxf(hm, 0.f); hx = fmaxf(hx, 0.f);
            om += w2[cc * 4 + rr] * hm;
            ox += w2[cc * 4 + rr] * hx;
        }
        const float gate = 1.f / (1.f + __expf(-(om + ox)));
        gates[t] = gate;
        e1S[t] = gate * S + X;
        e2S[t] = gate * gate * SS + 2.f * gate * SX + XX;
        __syncthreads();
        if (bb == 0) {
            const float sumY = e1S[t] + e1S[t + 64];
            const float sumY2 = e2S[t] + e2S[t + 64];
            const float meanY = sumY * (1.f / 131072.f);
            const float varY = sumY2 * (1.f / 131072.f) - meanY * meanY;
            const float sc = stream ? bn2_scale[cc] : bn1_scale[cc];
            const float bi = stream ? bn2_bias[cc] : bn1_bias[cc];
            const float Aa = sc * rsqrtf(varY + 1e-5f);
            AB[stream * 128 + cc] = Aa;
            AB[stream * 128 + 64 + cc] = bi - meanY * Aa;
        }
    }
}

// ---------- K4: final elementwise ----------
__global__ __launch_bounds__(256) void finalize(
    const bf16t* __restrict__ s1, const bf16t* __restrict__ s2,
    const float* __restrict__ x1, const float* __restrict__ x2,
    const float* __restrict__ gates, const float* __restrict__ AB,
    float* __restrict__ out)
{
    const size_t tid = (size_t)blockIdx.x * 256 + threadIdx.x;
    const size_t idx = tid * 4;
    const int b = (int)(idx >> 22);
    const int c = (int)((idx >> 16) & 63);
    const bool odd = (c & 1) != 0;
    const float g1 = gates[b * 64 + c], g2 = gates[128 + b * 64 + c];
    const float A1 = AB[c], B1 = AB[64 + c], A2 = AB[128 + c], B2 = AB[192 + c];

    const uint2 su1 = *(const uint2*)(s1 + idx);
    const uint2 su2 = *(const uint2*)(s2 + idx);
    const float4 x1v = *(const float4*)(x1 + idx);
    const float4 x2v = *(const float4*)(x2 + idx);
    float s1f[4] = {bflo(su1.x), bfhi(su1.x), bflo(su1.y), bfhi(su1.y)};
    float s2f[4] = {bflo(su2.x), bfhi(su2.x), bflo(su2.y), bfhi(su2.y)};
    float xa[4] = {x1v.x, x1v.y, x1v.z, x1v.w};
    float xb[4] = {x2v.x, x2v.y, x2v.z, x2v.w};
    float o1[4], o2[4];
#pragma unroll
    for (int j = 0; j < 4; j++) {
        const float y1 = g1 * s1f[j] + xa[j];
        const float y2 = g2 * s2f[j] + xb[j];
        o1[j] = odd ? fmaxf(A1 * y1 + B1, 0.f) : xa[j];
        o2[j] = odd ? fmaxf(A2 * y2 + B2, 0.f) : xb[j];
    }
    *(float4*)(out + idx) = make_float4(o1[0], o1[1], o1[2], o1[3]);
    *(float4*)(out + 8388608 + idx) = make_float4(o2[0], o2[1], o2[2], o2[3]);
}

// ---------- host ----------
extern "C" void kernel_launch(void* const* d_in, const int* in_sizes, int n_in,
                              void* d_out, int out_size, void* d_ws, size_t ws_size,
                              hipStream_t stream) {
    (void)in_sizes; (void)n_in; (void)out_size; (void)ws_size;
    const float* x1 = (const float*)d_in[0];
    const float* x2 = (const float*)d_in[1];
    const float* wq1 = (const float*)d_in[2];  const float* bq1 = (const float*)d_in[3];
    const float* wq2 = (const float*)d_in[4];  const float* bq2 = (const float*)d_in[5];
    const float* wk1 = (const float*)d_in[6];  const float* bk1 = (const float*)d_in[7];
    const float* wk2 = (const float*)d_in[8];  const float* bk2 = (const float*)d_in[9];
    const float* wv1 = (const float*)d_in[10]; const float* bv1 = (const float*)d_in[11];
    const float* wv2 = (const float*)d_in[12]; const float* bv2 = (const float*)d_in[13];
    const float* gamma1 = (const float*)d_in[14];
    const float* gamma2 = (const float*)d_in[15];
    const float* sc1_w1 = (const float*)d_in[16]; const float* sc1_b1 = (const float*)d_in[17];
    const float* sc1_w2 = (const float*)d_in[18]; const float* sc1_b2 = (const float*)d_in[19];
    const float* sc2_w1 = (const float*)d_in[20]; const float* sc2_b1 = (const float*)d_in[21];
    const float* sc2_w2 = (const float*)d_in[22]; const float* sc2_b2 = (const float*)d_in[23];
    const float* bn1_scale = (const float*)d_in[24]; const float* bn1_bias = (const float*)d_in[25];
    const float* bn2_scale = (const float*)d_in[26]; const float* bn2_bias = (const float*)d_in[27];

    char* p = (char*)d_ws;
    const size_t SZ_QK = 2097152;   // bf16 (B,8,H,W)
    const size_t SZ_V = 16777216;   // bf16 (B,64,H,W)
    const size_t SZ_ST = 524288;    // fp32 (B,H,W)

    bf16t* q1 = (bf16t*)(p + 0 * SZ_QK);
    bf16t* k1 = (bf16t*)(p + 1 * SZ_QK);
    bf16t* q2 = (bf16t*)(p + 2 * SZ_QK);
    bf16t* k2 = (bf16t*)(p + 3 * SZ_QK);
    bf16t* v1 = (bf16t*)(p + 4 * SZ_QK);
    bf16t* v2 = (bf16t*)(p + 4 * SZ_QK + SZ_V);
    size_t off = 4 * SZ_QK + 2 * SZ_V;
    bf16t* q1T = (bf16t*)(p + off + 0 * SZ_QK);
    bf16t* k1T = (bf16t*)(p + off + 1 * SZ_QK);
    bf16t* q2T = (bf16t*)(p + off + 2 * SZ_QK);
    bf16t* k2T = (bf16t*)(p + off + 3 * SZ_QK);
    bf16t* v1T = (bf16t*)(p + off + 4 * SZ_QK);
    bf16t* v2T = (bf16t*)(p + off + 4 * SZ_QK + SZ_V);
    off += 4 * SZ_QK + 2 * SZ_V;
    bf16t* oH1T = (bf16t*)(p + off); off += SZ_V;
    bf16t* oH2T = (bf16t*)(p + off); off += SZ_V;
    bf16t* oW1 = (bf16t*)(p + off); off += SZ_V;
    bf16t* oW2 = (bf16t*)(p + off); off += SZ_V;
    float* sH1 = (float*)(p + off); off += SZ_ST;   // column-pass frame [b][w][h]
    float* sH2 = (float*)(p + off); off += SZ_ST;
    float* sW1 = (float*)(p + off); off += SZ_ST;
    float* sW2 = (float*)(p + off); off += SZ_ST;
    float* accum = (float*)(p + off);                  // 1280 f32
    unsigned* accmax = (unsigned*)(p + off + 5120);    // 256 u32
    unsigned* done = (unsigned*)(p + off + 6144);      // 1 u32 (+pad)
    float* gates = (float*)(p + off + 7168);
    float* AB = (float*)(p + off + 8192);

    // s1/s2 overlay the dead v1T/v2T (oH1T/oH2T survive into combine)
    bf16t* s1 = v1T;
    bf16t* s2 = v2T;

    // K1: MFMA convs (+ accum/done zeroing)
    ConvArgs CA;
    CA.x[0] = x1; CA.x[1] = x2;
    CA.wq[0] = wq1; CA.wq[1] = wq2; CA.bq[0] = bq1; CA.bq[1] = bq2;
    CA.wk[0] = wk1; CA.wk[1] = wk2; CA.bk[0] = bk1; CA.bk[1] = bk2;
    CA.wv[0] = wv1; CA.wv[1] = wv2; CA.bv[0] = bv1; CA.bv[1] = bv2;
    CA.q[0] = q1; CA.q[1] = q2; CA.k[0] = k1; CA.k[1] = k2;
    CA.v[0] = v1; CA.v[1] = v2;
    CA.zeroR = (unsigned*)accum;
    conv_qkv<<<dim3(256, 1, 4), 256, 0, stream>>>(CA);

    // K2: all input transposes (q1..k2 = 64 slices, v1,v2 = 256)
    transpose16<<<dim3(4, 4, 320), 256, 0, stream>>>(q1, q1T);

    // K3: fused criss-cross
    RowccArgs RA;
    RA.q[0] = q2T; RA.k[0] = k1T; RA.v[0] = v1T; RA.o[0] = oH1T; RA.so[0] = sH1;
    RA.q[1] = q1T; RA.k[1] = k2T; RA.v[1] = v2T; RA.o[1] = oH2T; RA.so[1] = sH2;
    RA.q[2] = q2;  RA.k[2] = k1;  RA.v[2] = v1;  RA.o[2] = oW1;  RA.so[2] = sW1;
    RA.q[3] = q1;  RA.k[3] = k2;  RA.v[3] = v2;  RA.o[3] = oW2;  RA.so[3] = sW2;
    rowcc_mfma<<<dim3(256, 2, 4), 256, 0, stream>>>(RA);

    // K4: combine (+ last-block gates/BN)
    combine_reduce<<<dim3(8, 64, 2), 256, 0, stream>>>(
        oH1T, oW1, oH2T, oW2, sH1, sW1, sH2, sW2, x1, x2, gamma1, gamma2,
        s1, s2, accum, accmax, done,
        sc1_w1, sc1_b1, sc1_w2, sc1_b2,
        sc2_w1, sc2_b1, sc2_w2, sc2_b2,
        bn1_scale, bn1_bias, bn2_scale, bn2_bias,
        gates, AB);

    // K5: finalize
    finalize<<<8192, 256, 0, stream>>>(s1, s2, x1, x2, gates, AB, (float*)d_out);
}